// Round 6
// baseline (570.082 us; speedup 1.0000x reference)
//
#include <hip/hip_runtime.h>

#define HH 8
#define LL 256
#define CC 32
#define NS1 2           // s1 per block: 1024 blocks = all co-resident, bias demand halved
#define VT_STRIDE 264   // padded sk2 stride for V^T, multiple of 8 (b128 align)

typedef _Float16 f16x8 __attribute__((ext_vector_type(8)));
typedef _Float16 f16x4 __attribute__((ext_vector_type(4)));
typedef float    f32x4 __attribute__((ext_vector_type(4)));
typedef int      i32x4 __attribute__((ext_vector_type(4)));
typedef unsigned int u32x2 __attribute__((ext_vector_type(2)));

// Transpose bias (B=1, s2, sk2, H) -> biasT [H][s2][sk2] so the main kernel's
// bias loads become lane-coalesced float4.
__global__ __launch_bounds__(256)
void bias_transpose(const float* __restrict__ bias, float* __restrict__ biasT) {
    const int g = blockIdx.x * 256 + threadIdx.x;   // g = h*65536 + s2*256 + sk2
    const int h = g >> 16;
    const int s2sk2 = g & 65535;
    biasT[g] = bias[(s2sk2 << 3) | h];
}

// Flash-split over sk2 (two 128-wide halves, online softmax).
// Latency-focused round: dur was pinned at ~334us across FETCH 716-842MB
// (R0-R5) => latency-bound, not traffic-bound. Changes:
//  - PV P-fragment exchange via ds_bpermute (__shfl) instead of LDS
//    write->read round-trip (removes 2 lgkm waits x 32 chunks/wave).
//  - bias register pipelining: half-0 issued at strip top, half-1 issued
//    as soon as half-0 is consumed (miss latency hidden under softmax+PV).
//  - gate prefetched at strip top.
//  - NS1=2: second s1's bias rows are L2-hot (short reuse distance).
__global__ __launch_bounds__(256, 4)
void triattn(const float* __restrict__ q, const float* __restrict__ k,
             const float* __restrict__ v, const float* __restrict__ bias,
             const float* __restrict__ biasT,   // may be null -> fallback path
             const float* __restrict__ gate, float* __restrict__ out) {
    __shared__ _Float16 Klds[LL * CC];            // [sk2][32]      16384 B
    __shared__ _Float16 Vt[CC * VT_STRIDE];       // [c][sk2]       16896 B

    const int h    = blockIdx.y;
    const int s1b  = blockIdx.x * NS1;
    const int tid  = threadIdx.x;
    const int wave = tid >> 6;
    const int lane = tid & 63;
    const int n16  = lane & 15;
    const int quad = lane >> 4;

    // P-fragment exchange lanes: dest (n16,quad) takes pf[0:3] from src0,
    // pf[4:7] from src1; tile select (t0 vs t1) by quad>=2.
    const int  src0 = n16 + ((quad & 1) << 5);
    const int  src1 = src0 + 16;
    const bool hiq  = quad >= 2;

    #pragma unroll 1
    for (int s1i = 0; s1i < NS1; ++s1i) {
        const int s1 = s1b + s1i;
        const size_t base = ((size_t)(h * LL + s1)) * (LL * CC);
        const float* qb = q + base;
        const float* kb = k + base;
        const float* vb = v + base;
        float*       ob = out + base;
        const float* gateb = gate + ((size_t)s1 * (LL * CC * HH)) + h;

        // ---- issue strip-0 Q loads early (hidden under K/V staging) ----
        f32x4 qA, qB;
        {
            const f32x4* qr4 = (const f32x4*)(qb + (size_t)(wave * 64 + n16) * CC + quad * 8);
            qA = __builtin_nontemporal_load(qr4);
            qB = __builtin_nontemporal_load(qr4 + 1);
        }

        // ---- stage K and V^T into LDS as fp16 (NT: stream-once, read-only) ----
        const f32x4* k4 = (const f32x4*)kb;
        const f32x4* v4 = (const f32x4*)vb;
        #pragma unroll
        for (int i = 0; i < 8; ++i) {
            const int idx = tid + i * 256;        // f32x4 index over 2048
            const int row = idx >> 3;             // sk2
            const int c0  = (idx & 7) * 4;        // channel base
            f32x4 f = __builtin_nontemporal_load(k4 + idx);
            f16x4 kv4 = { (_Float16)f[0], (_Float16)f[1], (_Float16)f[2], (_Float16)f[3] };
            *(f16x4*)&Klds[row * CC + c0] = kv4;
            f32x4 g = __builtin_nontemporal_load(v4 + idx);
            _Float16* vd = &Vt[c0 * VT_STRIDE + row];
            vd[0]             = (_Float16)g[0];
            vd[VT_STRIDE]     = (_Float16)g[1];
            vd[2 * VT_STRIDE] = (_Float16)g[2];
            vd[3 * VT_STRIDE] = (_Float16)g[3];
        }
        __syncthreads();

        #pragma unroll 1
        for (int si = 0; si < 4; ++si) {
            const int strip = wave * 4 + si;
            const int r0 = strip * 16;            // s2 base for this strip

            // Q as B-operand fragment: B[k=c=quad*8+j][n=s2=n16]
            f16x8 qf;
            qf[0] = (_Float16)qA[0]; qf[1] = (_Float16)qA[1];
            qf[2] = (_Float16)qA[2]; qf[3] = (_Float16)qA[3];
            qf[4] = (_Float16)qB[0]; qf[5] = (_Float16)qB[1];
            qf[6] = (_Float16)qB[2]; qf[7] = (_Float16)qB[3];

            // prefetch next strip's Q (consumed at next iteration's top)
            if (si < 3) {
                const f32x4* qr4 = (const f32x4*)(qb + (size_t)(r0 + 16 + n16) * CC + quad * 8);
                qA = __builtin_nontemporal_load(qr4);
                qB = __builtin_nontemporal_load(qr4 + 1);
            }

            // ---- gate prefetch (consumed in epilogue, far away) ----
            float gp0[4], gp1[4];
            #pragma unroll
            for (int r = 0; r < 4; ++r) {
                const int s2 = r0 + quad * 4 + r;
                gp0[r] = gateb[(s2 * CC + n16) * HH];
                gp1[r] = gateb[(s2 * CC + 16 + n16) * HH];
            }

            // ---- bias half-0 issue (consumed after QK^T MFMAs) ----
            const f32x4* bb = biasT
                ? (const f32x4*)(biasT + ((size_t)h << 16) + (size_t)(r0 + n16) * LL) + quad
                : nullptr;
            const float* bb2 = bias + h + ((size_t)(r0 + n16) * LL + quad * 4) * HH;
            f32x4 bv[8];
            if (bb) {
                #pragma unroll
                for (int t = 0; t < 8; ++t) bv[t] = bb[t * 4];
            } else {
                #pragma unroll
                for (int t = 0; t < 8; ++t)
                    #pragma unroll
                    for (int r = 0; r < 4; ++r) bv[t][r] = bb2[(t * 16 + r) * HH];
            }

            f32x4 o0 = {0.f, 0.f, 0.f, 0.f}, o1 = {0.f, 0.f, 0.f, 0.f};
            float mrow, srow;
            f32x4 acc[8];

            // ================= half 0 (sk2 0..127) =================
            #pragma unroll
            for (int t = 0; t < 8; ++t) {
                f16x8 kf = *(const f16x8*)&Klds[(t * 16 + n16) * CC + quad * 8];
                f32x4 z = {0.f, 0.f, 0.f, 0.f};
                acc[t] = __builtin_amdgcn_mfma_f32_16x16x32_f16(kf, qf, z, 0, 0, 0);
            }
            #pragma unroll
            for (int t = 0; t < 8; ++t) {
                acc[t][0] += bv[t][0]; acc[t][1] += bv[t][1];
                acc[t][2] += bv[t][2]; acc[t][3] += bv[t][3];
            }
            // bias half-1 issue NOW (bv dead): latency hides under softmax+PV0
            f32x4 bw[8];
            if (bb) {
                #pragma unroll
                for (int t = 0; t < 8; ++t) bw[t] = bb[(8 + t) * 4];
            } else {
                #pragma unroll
                for (int t = 0; t < 8; ++t)
                    #pragma unroll
                    for (int r = 0; r < 4; ++r) bw[t][r] = bb2[((8 + t) * 16 + r) * HH];
            }

            {   // softmax init (rows = s2 = n16)
                f32x4 mv = acc[0];
                #pragma unroll
                for (int t = 1; t < 8; ++t) {
                    mv[0] = fmaxf(mv[0], acc[t][0]); mv[1] = fmaxf(mv[1], acc[t][1]);
                    mv[2] = fmaxf(mv[2], acc[t][2]); mv[3] = fmaxf(mv[3], acc[t][3]);
                }
                float ml = fmaxf(fmaxf(mv[0], mv[1]), fmaxf(mv[2], mv[3]));
                ml = fmaxf(ml, __shfl_xor(ml, 16));
                ml = fmaxf(ml, __shfl_xor(ml, 32));
                f32x4 sv = {0.f, 0.f, 0.f, 0.f};
                #pragma unroll
                for (int t = 0; t < 8; ++t) {
                    #pragma unroll
                    for (int r = 0; r < 4; ++r) {
                        float p = exp2f((acc[t][r] - ml) * 1.44269504f);
                        acc[t][r] = p;
                        sv[r] += p;
                    }
                }
                float sl = (sv[0] + sv[1]) + (sv[2] + sv[3]);
                sl += __shfl_xor(sl, 16);
                sl += __shfl_xor(sl, 32);
                srow = sl;
                mrow = ml;
            }

            // PV half 0: P-fragment via ds_bpermute exchange (no LDS round-trip)
            #define PV_HALF(HHC)                                                        \
                _Pragma("unroll")                                                       \
                for (int kl = 0; kl < 4; ++kl) {                                        \
                    const int kg = (HHC) * 4 + kl;                                      \
                    f16x4 pa = { (_Float16)acc[2*kl][0],   (_Float16)acc[2*kl][1],      \
                                 (_Float16)acc[2*kl][2],   (_Float16)acc[2*kl][3] };    \
                    f16x4 pb = { (_Float16)acc[2*kl+1][0], (_Float16)acc[2*kl+1][1],    \
                                 (_Float16)acc[2*kl+1][2], (_Float16)acc[2*kl+1][3] };  \
                    u32x2 ua = __builtin_bit_cast(u32x2, pa);                           \
                    u32x2 ub = __builtin_bit_cast(u32x2, pb);                           \
                    int a0 = __shfl((int)ua[0], src0), a1 = __shfl((int)ua[1], src0);   \
                    int a2 = __shfl((int)ua[0], src1), a3 = __shfl((int)ua[1], src1);   \
                    int b0 = __shfl((int)ub[0], src0), b1 = __shfl((int)ub[1], src0);   \
                    int b2 = __shfl((int)ub[0], src1), b3 = __shfl((int)ub[1], src1);   \
                    i32x4 pfi = { hiq ? b0 : a0, hiq ? b1 : a1,                         \
                                  hiq ? b2 : a2, hiq ? b3 : a3 };                       \
                    f16x8 pf = __builtin_bit_cast(f16x8, pfi);                          \
                    f16x8 vf0 = *(const f16x8*)&Vt[n16 * VT_STRIDE + kg * 32 + quad * 8];        \
                    f16x8 vf1 = *(const f16x8*)&Vt[(16 + n16) * VT_STRIDE + kg * 32 + quad * 8]; \
                    o0 = __builtin_amdgcn_mfma_f32_16x16x32_f16(pf, vf0, o0, 0, 0, 0);  \
                    o1 = __builtin_amdgcn_mfma_f32_16x16x32_f16(pf, vf1, o1, 0, 0, 0);  \
                }
            PV_HALF(0)

            // ================= half 1 (sk2 128..255) =================
            #pragma unroll
            for (int t = 0; t < 8; ++t) {
                f16x8 kf = *(const f16x8*)&Klds[((8 + t) * 16 + n16) * CC + quad * 8];
                f32x4 z = {0.f, 0.f, 0.f, 0.f};
                acc[t] = __builtin_amdgcn_mfma_f32_16x16x32_f16(kf, qf, z, 0, 0, 0);
            }
            #pragma unroll
            for (int t = 0; t < 8; ++t) {
                acc[t][0] += bw[t][0]; acc[t][1] += bw[t][1];
                acc[t][2] += bw[t][2]; acc[t][3] += bw[t][3];
            }

            {   // softmax combine
                f32x4 mv = acc[0];
                #pragma unroll
                for (int t = 1; t < 8; ++t) {
                    mv[0] = fmaxf(mv[0], acc[t][0]); mv[1] = fmaxf(mv[1], acc[t][1]);
                    mv[2] = fmaxf(mv[2], acc[t][2]); mv[3] = fmaxf(mv[3], acc[t][3]);
                }
                float ml = fmaxf(fmaxf(mv[0], mv[1]), fmaxf(mv[2], mv[3]));
                ml = fmaxf(ml, __shfl_xor(ml, 16));
                ml = fmaxf(ml, __shfl_xor(ml, 32));
                const float mNew = fmaxf(mrow, ml);
                f32x4 sv = {0.f, 0.f, 0.f, 0.f};
                #pragma unroll
                for (int t = 0; t < 8; ++t) {
                    #pragma unroll
                    for (int r = 0; r < 4; ++r) {
                        float p = exp2f((acc[t][r] - mNew) * 1.44269504f);
                        acc[t][r] = p;
                        sv[r] += p;
                    }
                }
                float sl = (sv[0] + sv[1]) + (sv[2] + sv[3]);
                sl += __shfl_xor(sl, 16);
                sl += __shfl_xor(sl, 32);
                const float alpha = exp2f((mrow - mNew) * 1.44269504f);
                srow = srow * alpha + sl;
                #pragma unroll
                for (int r = 0; r < 4; ++r) {
                    const float ar = __shfl(alpha, quad * 4 + r);
                    o0[r] *= ar; o1[r] *= ar;
                }
            }
            PV_HALF(1)
            #undef PV_HALF

            // ---- epilogue: normalize (shuffled inv), prefetched gate, store ----
            const float inv = 1.f / srow;   // per s2-row (indexed by n16)
            #pragma unroll
            for (int r = 0; r < 4; ++r) {
                const float wr = __shfl(inv, quad * 4 + r);
                const int s2 = r0 + quad * 4 + r;
                ob[(size_t)s2 * CC + n16]      = o0[r] * wr * gp0[r];
                ob[(size_t)s2 * CC + 16 + n16] = o1[r] * wr * gp1[r];
            }
        }
        // protect LDS (K/V) against next s1 iteration's re-staging
        __syncthreads();
    }
}

extern "C" void kernel_launch(void* const* d_in, const int* in_sizes, int n_in,
                              void* d_out, int out_size, void* d_ws, size_t ws_size,
                              hipStream_t stream) {
    const float* q    = (const float*)d_in[0];
    const float* k    = (const float*)d_in[1];
    const float* v    = (const float*)d_in[2];
    const float* bias = (const float*)d_in[3];
    const float* gate = (const float*)d_in[4];
    float* out = (float*)d_out;

    float* biasT = nullptr;
    if (ws_size >= (size_t)HH * LL * LL * sizeof(float)) {
        biasT = (float*)d_ws;
        bias_transpose<<<dim3((HH * LL * LL) / 256), 256, 0, stream>>>(bias, biasT);
    }
    dim3 grid(LL / NS1, HH);
    triattn<<<grid, 256, 0, stream>>>(q, k, v, bias, biasT, gate, out);
}

// Round 7
// 529.938 us; speedup vs baseline: 1.0758x; 1.0758x over previous
//
#include <hip/hip_runtime.h>

#define HH 8
#define LL 256
#define CC 32
#define VT_STRIDE 264   // padded sk2 stride for V^T, multiple of 8 (b128 align)
#define PC_STRIDE 40    // per-wave P chunk stride, multiple of 8 (b128 align)

typedef _Float16 f16x8 __attribute__((ext_vector_type(8)));
typedef _Float16 f16x4 __attribute__((ext_vector_type(4)));
typedef float    f32x4 __attribute__((ext_vector_type(4)));

// Transpose+compress bias (B=1, s2, sk2, H) f32 -> biasT16 [H][s2][sk2] fp16.
// bias is the single biggest HBM term (~460 MB of misses: 512 MB stream demand
// on a 2 MB array whose L2 lines are churned out between re-references).
// fp16 halves the miss bytes BY CONSTRUCTION, independent of L2 behavior.
__global__ __launch_bounds__(256)
void bias_transpose16(const float* __restrict__ bias, _Float16* __restrict__ biasT16) {
    const int g = blockIdx.x * 256 + threadIdx.x;   // g = h*65536 + s2*256 + sk2
    const int h = g >> 16;
    const int s2sk2 = g & 65535;
    biasT16[g] = (_Float16)bias[(s2sk2 << 3) | h];  // writes coalesced (2B x 256 consecutive)
}

// Transpose+compress gate (1, s1, s2, C*H) f32 -> gateT16 [H][s1*s2][C] fp16.
// Raw-gate scalar reads touched ~512 MB of lines (~130 MB missed); gateT16 is
// a 32 MB private stream.
__global__ __launch_bounds__(256)
void gate_transpose16(const float* __restrict__ gate, _Float16* __restrict__ gateT16) {
    __shared__ float t[32 * 264];                 // 32 rows x 256ch, pad to 264
    const int row0 = blockIdx.x * 32;             // flattened s1*256+s2 row base
    const int tid  = threadIdx.x;
    #pragma unroll
    for (int i = 0; i < 8; ++i) {
        const int idx = i * 256 + tid;            // f32x4 index over 32x64
        const int r   = idx >> 6;
        const int c4  = idx & 63;
        f32x4 f = __builtin_nontemporal_load(
            ((const f32x4*)gate) + (size_t)(row0 + r) * 64 + c4);
        *(f32x4*)&t[r * 264 + c4 * 4] = f;
    }
    __syncthreads();
    const int r  = tid >> 3;                      // 0..31 tile row
    const int c4 = tid & 7;                       // output f16x4 within row
    #pragma unroll
    for (int h = 0; h < HH; ++h) {
        f16x4 o = { (_Float16)t[r * 264 + (c4 * 4 + 0) * 8 + h],
                    (_Float16)t[r * 264 + (c4 * 4 + 1) * 8 + h],
                    (_Float16)t[r * 264 + (c4 * 4 + 2) * 8 + h],
                    (_Float16)t[r * 264 + (c4 * 4 + 3) * 8 + h] };
        *(f16x4*)&gateT16[((size_t)h * (LL * LL) + row0 + r) * CC + c4 * 4] = o;
    }
}

// Flash-split over sk2 (two 128-wide halves, online softmax), R3-verified core.
// (256,4): cap 128 regs, 4 blocks/CU at 38.4 KB LDS.
// Memory-bound at ~3.45 TB/s effective (dur == hbm_bytes/3.45 across R0-R6);
// this round shrinks bytes: fp16 bias stream (-~230 MB) + fp16 gate (-~100 MB).
__global__ __launch_bounds__(256, 4)
void triattn(const float* __restrict__ q, const float* __restrict__ k,
             const float* __restrict__ v, const float* __restrict__ bias,
             const _Float16* __restrict__ biasT16,   // may be null -> raw fallback
             const float* __restrict__ gate,         // raw layout (fallback)
             const _Float16* __restrict__ gateT16,   // may be null -> raw fallback
             float* __restrict__ out) {
    __shared__ _Float16 Klds[LL * CC];            // [sk2][32]      16384 B
    __shared__ _Float16 Vt[CC * VT_STRIDE];       // [c][sk2]       16896 B
    __shared__ _Float16 Pc[4][16 * PC_STRIDE];    // per-wave chunk  5120 B

    const int h    = blockIdx.y;
    const int s1   = blockIdx.x;
    const int tid  = threadIdx.x;
    const int wave = tid >> 6;
    const int lane = tid & 63;
    const int n16  = lane & 15;
    const int quad = lane >> 4;

    const size_t base = ((size_t)(h * LL + s1)) * (LL * CC);
    const float* qb = q + base;
    const float* kb = k + base;
    const float* vb = v + base;
    float*       ob = out + base;
    const float*    gateb   = gate + ((size_t)s1 * (LL * CC * HH)) + h;
    const _Float16* gateTb  = gateT16 ? (gateT16 + ((size_t)(h * LL + s1) * LL) * CC) : nullptr;

    // ---- issue strip-0 Q fragment loads early (hidden under K/V staging) ----
    f32x4 qA, qB;
    {
        const f32x4* qr4 = (const f32x4*)(qb + (size_t)(wave * 64 + n16) * CC + quad * 8);
        qA = __builtin_nontemporal_load(qr4);
        qB = __builtin_nontemporal_load(qr4 + 1);
    }

    // ---- stage K and V^T into LDS as fp16 (NT loads: stream-once, read-only) ----
    const f32x4* k4 = (const f32x4*)kb;
    const f32x4* v4 = (const f32x4*)vb;
    #pragma unroll
    for (int i = 0; i < 8; ++i) {
        const int idx = tid + i * 256;        // f32x4 index over 2048
        const int row = idx >> 3;             // sk2
        const int c0  = (idx & 7) * 4;        // channel base
        f32x4 f = __builtin_nontemporal_load(k4 + idx);
        f16x4 kv4 = { (_Float16)f[0], (_Float16)f[1], (_Float16)f[2], (_Float16)f[3] };
        *(f16x4*)&Klds[row * CC + c0] = kv4;
        f32x4 g = __builtin_nontemporal_load(v4 + idx);
        _Float16* vd = &Vt[c0 * VT_STRIDE + row];
        vd[0]             = (_Float16)g[0];
        vd[VT_STRIDE]     = (_Float16)g[1];
        vd[2 * VT_STRIDE] = (_Float16)g[2];
        vd[3 * VT_STRIDE] = (_Float16)g[3];
    }
    __syncthreads();

    _Float16* pw = Pc[wave];

    #pragma unroll 1
    for (int si = 0; si < 4; ++si) {
        const int strip = wave * 4 + si;
        const int r0 = strip * 16;            // s2 base for this strip

        // Q as B-operand fragment: B[k=c=quad*8+j][n=s2=n16]
        f16x8 qf;
        qf[0] = (_Float16)qA[0]; qf[1] = (_Float16)qA[1];
        qf[2] = (_Float16)qA[2]; qf[3] = (_Float16)qA[3];
        qf[4] = (_Float16)qB[0]; qf[5] = (_Float16)qB[1];
        qf[6] = (_Float16)qB[2]; qf[7] = (_Float16)qB[3];

        // prefetch next strip's Q (consumed at next iteration's top)
        if (si < 3) {
            const f32x4* qr4 = (const f32x4*)(qb + (size_t)(r0 + 16 + n16) * CC + quad * 8);
            qA = __builtin_nontemporal_load(qr4);
            qB = __builtin_nontemporal_load(qr4 + 1);
        }

        f32x4 o0 = {0.f, 0.f, 0.f, 0.f}, o1 = {0.f, 0.f, 0.f, 0.f};
        float mrow = 0.f;   // valid after hh=0
        float srow = 0.f;

        #pragma unroll
        for (int hh = 0; hh < 2; ++hh) {
            // ---- S^T half: acc[t] row = sk2 = (hh*8+t)*16+quad*4+r, col = s2 = n16 ----
            f32x4 acc[8];
            #pragma unroll
            for (int t = 0; t < 8; ++t) {
                f16x8 kf = *(const f16x8*)&Klds[((hh * 8 + t) * 16 + n16) * CC + quad * 8];
                f32x4 z = {0.f, 0.f, 0.f, 0.f};
                acc[t] = __builtin_amdgcn_mfma_f32_16x16x32_f16(kf, qf, z, 0, 0, 0);
            }

            // ---- bias add: bias[s2 = r0+n16][sk2 = (hh*8+t)*16+quad*4+r] ----
            if (biasT16) {
                // fp16 biasT: 8B f16x4 per t, lane-coalesced
                const f16x4* bb = (const f16x4*)(biasT16 + ((size_t)h << 16)
                                                 + (size_t)(r0 + n16) * LL) + quad;
                #pragma unroll
                for (int t = 0; t < 8; ++t) {
                    f16x4 bv = bb[(hh * 8 + t) * 4];
                    acc[t][0] += (float)bv[0]; acc[t][1] += (float)bv[1];
                    acc[t][2] += (float)bv[2]; acc[t][3] += (float)bv[3];
                }
            } else {
                const float* bb2 = bias + h + ((size_t)(r0 + n16) * LL + quad * 4) * HH;
                #pragma unroll
                for (int t = 0; t < 8; ++t)
                    #pragma unroll
                    for (int r = 0; r < 4; ++r)
                        acc[t][r] += bb2[((hh * 8 + t) * 16 + r) * HH];
            }

            // ---- local row-max (rows = s2 = n16; quad-uniform after shuffles) ----
            f32x4 mv = acc[0];
            #pragma unroll
            for (int t = 1; t < 8; ++t) {
                mv[0] = fmaxf(mv[0], acc[t][0]); mv[1] = fmaxf(mv[1], acc[t][1]);
                mv[2] = fmaxf(mv[2], acc[t][2]); mv[3] = fmaxf(mv[3], acc[t][3]);
            }
            float ml = fmaxf(fmaxf(mv[0], mv[1]), fmaxf(mv[2], mv[3]));
            ml = fmaxf(ml, __shfl_xor(ml, 16));
            ml = fmaxf(ml, __shfl_xor(ml, 32));

            const float mNew = (hh == 0) ? ml : fmaxf(mrow, ml);

            // ---- exp + local sum ----
            f32x4 sv = {0.f, 0.f, 0.f, 0.f};
            #pragma unroll
            for (int t = 0; t < 8; ++t) {
                #pragma unroll
                for (int r = 0; r < 4; ++r) {
                    float p = exp2f((acc[t][r] - mNew) * 1.44269504f);
                    acc[t][r] = p;
                    sv[r] += p;
                }
            }
            float sl = (sv[0] + sv[1]) + (sv[2] + sv[3]);
            sl += __shfl_xor(sl, 16);
            sl += __shfl_xor(sl, 32);

            if (hh == 0) {
                srow = sl;
            } else {
                const float alpha = exp2f((mrow - mNew) * 1.44269504f);
                srow = srow * alpha + sl;
                // rescale o BEFORE accumulating this half's PV
                #pragma unroll
                for (int r = 0; r < 4; ++r) {
                    const float ar = __shfl(alpha, quad * 4 + r);
                    o0[r] *= ar; o1[r] *= ar;
                }
            }
            mrow = mNew;

            // ---- PV for this half: kk chunks of 32 sk2 ----
            #pragma unroll
            for (int kl = 0; kl < 4; ++kl) {
                const int kg = hh * 4 + kl;
                const int t0 = 2 * kl, t1 = 2 * kl + 1;
                f16x4 pa = { (_Float16)acc[t0][0], (_Float16)acc[t0][1],
                             (_Float16)acc[t0][2], (_Float16)acc[t0][3] };
                f16x4 pb = { (_Float16)acc[t1][0], (_Float16)acc[t1][1],
                             (_Float16)acc[t1][2], (_Float16)acc[t1][3] };
                *(f16x4*)&pw[n16 * PC_STRIDE + quad * 4]      = pa;
                *(f16x4*)&pw[n16 * PC_STRIDE + 16 + quad * 4] = pb;
                // same-wave DS ops are in-order: read sees this chunk's data,
                // and the next chunk's overwrite cannot pass this read.
                f16x8 pf  = *(const f16x8*)&pw[n16 * PC_STRIDE + quad * 8];
                f16x8 vf0 = *(const f16x8*)&Vt[n16 * VT_STRIDE + kg * 32 + quad * 8];
                f16x8 vf1 = *(const f16x8*)&Vt[(16 + n16) * VT_STRIDE + kg * 32 + quad * 8];
                o0 = __builtin_amdgcn_mfma_f32_16x16x32_f16(pf, vf0, o0, 0, 0, 0);
                o1 = __builtin_amdgcn_mfma_f32_16x16x32_f16(pf, vf1, o1, 0, 0, 0);
            }
        }

        // ---- epilogue: normalize (shuffled inv), gate, plain store ----
        const float inv = 1.f / srow;   // per s2-row (indexed by n16)
        #pragma unroll
        for (int r = 0; r < 4; ++r) {
            const float wr = __shfl(inv, quad * 4 + r);
            const int s2 = r0 + quad * 4 + r;
            float g0, g1;
            if (gateTb) {
                g0 = (float)gateTb[(size_t)s2 * CC + n16];
                g1 = (float)gateTb[(size_t)s2 * CC + 16 + n16];
            } else {
                g0 = gateb[(s2 * CC + n16) * HH];
                g1 = gateb[(s2 * CC + 16 + n16) * HH];
            }
            ob[(size_t)s2 * CC + n16]      = o0[r] * wr * g0;
            ob[(size_t)s2 * CC + 16 + n16] = o1[r] * wr * g1;
        }
    }
}

extern "C" void kernel_launch(void* const* d_in, const int* in_sizes, int n_in,
                              void* d_out, int out_size, void* d_ws, size_t ws_size,
                              hipStream_t stream) {
    const float* q    = (const float*)d_in[0];
    const float* k    = (const float*)d_in[1];
    const float* v    = (const float*)d_in[2];
    const float* bias = (const float*)d_in[3];
    const float* gate = (const float*)d_in[4];
    float* out = (float*)d_out;

    const size_t bias_elems = (size_t)HH * LL * LL;            // 512K fp16 = 1 MB
    const size_t gate_elems = (size_t)HH * LL * LL * CC;       // 16M fp16 = 32 MB
    const size_t need = (bias_elems + gate_elems) * sizeof(_Float16);

    _Float16* biasT16 = nullptr;
    _Float16* gateT16 = nullptr;
    if (ws_size >= need) {
        biasT16 = (_Float16*)d_ws;
        gateT16 = biasT16 + bias_elems;
        bias_transpose16<<<dim3((HH * LL * LL) / 256), 256, 0, stream>>>(bias, biasT16);
        gate_transpose16<<<dim3((LL * LL) / 32), 256, 0, stream>>>(gate, gateT16);
    }
    dim3 grid(LL, HH);
    triattn<<<grid, 256, 0, stream>>>(q, k, v, bias, biasT16, gate, gateT16, out);
}

// Round 8
// 324.561 us; speedup vs baseline: 1.7565x; 1.6328x over previous
//
#include <hip/hip_runtime.h>

#define HH 8
#define LL 256
#define CC 32
#define VT_STRIDE 264   // padded sk2 stride for V^T, multiple of 8 (b128 align)
#define PC_STRIDE 40    // per-wave P chunk stride, multiple of 8 (b128 align)

typedef _Float16 f16x8 __attribute__((ext_vector_type(8)));
typedef _Float16 f16x4 __attribute__((ext_vector_type(4)));
typedef float    f32x4 __attribute__((ext_vector_type(4)));

// Transpose bias (B=1, s2, sk2, H) -> biasT [H][s2][sk2] so the main kernel's
// bias loads become lane-coalesced float4. (R7 showed bias re-reads are mostly
// L2-absorbed; f32 biasT is the verified-best variant.)
__global__ __launch_bounds__(256)
void bias_transpose(const float* __restrict__ bias, float* __restrict__ biasT) {
    const int g = blockIdx.x * 256 + threadIdx.x;   // g = h*65536 + s2*256 + sk2
    const int h = g >> 16;
    const int s2sk2 = g & 65535;
    biasT[g] = bias[(s2sk2 << 3) | h];
}

// Flash-split over sk2 (two 128-wide halves, online softmax), R0-verified core.
// (256,4): cap 128 regs, 4 blocks/CU at 38.4 KB LDS.
// This round: full-line output stores. The epilogue's 64B-segment scatter is
// the last unexplained traffic term (WRITE 307-462 MB vs 67 MB of output +
// matching RMW fetches). Stage normalized+gated values through per-wave LDS
// (Pc reuse, asm-fenced) and store 1KB contiguous line-aligned bursts.
__global__ __launch_bounds__(256, 4)
void triattn(const float* __restrict__ q, const float* __restrict__ k,
             const float* __restrict__ v, const float* __restrict__ bias,
             const float* __restrict__ biasT,   // may be null -> fallback path
             const float* __restrict__ gate, float* __restrict__ out) {
    __shared__ _Float16 Klds[LL * CC];            // [sk2][32]      16384 B
    __shared__ _Float16 Vt[CC * VT_STRIDE];       // [c][sk2]       16896 B
    __shared__ _Float16 Pc[4][16 * PC_STRIDE];    // per-wave chunk  5120 B
                                                  // (reused as 1KB f32 out-stage)

    const int h    = blockIdx.y;
    const int s1   = blockIdx.x;
    const int tid  = threadIdx.x;
    const int wave = tid >> 6;
    const int lane = tid & 63;
    const int n16  = lane & 15;
    const int quad = lane >> 4;

    const size_t base = ((size_t)(h * LL + s1)) * (LL * CC);
    const float* qb = q + base;
    const float* kb = k + base;
    const float* vb = v + base;
    float*       ob = out + base;
    const float* gateb = gate + ((size_t)s1 * (LL * CC * HH)) + h;

    // ---- issue strip-0 Q fragment loads early (hidden under K/V staging) ----
    f32x4 qA, qB;
    {
        const f32x4* qr4 = (const f32x4*)(qb + (size_t)(wave * 64 + n16) * CC + quad * 8);
        qA = __builtin_nontemporal_load(qr4);
        qB = __builtin_nontemporal_load(qr4 + 1);
    }

    // ---- stage K and V^T into LDS as fp16 (NT loads: stream-once, read-only) ----
    const f32x4* k4 = (const f32x4*)kb;
    const f32x4* v4 = (const f32x4*)vb;
    #pragma unroll
    for (int i = 0; i < 8; ++i) {
        const int idx = tid + i * 256;        // f32x4 index over 2048
        const int row = idx >> 3;             // sk2
        const int c0  = (idx & 7) * 4;        // channel base
        f32x4 f = __builtin_nontemporal_load(k4 + idx);
        f16x4 kv4 = { (_Float16)f[0], (_Float16)f[1], (_Float16)f[2], (_Float16)f[3] };
        *(f16x4*)&Klds[row * CC + c0] = kv4;
        f32x4 g = __builtin_nontemporal_load(v4 + idx);
        _Float16* vd = &Vt[c0 * VT_STRIDE + row];
        vd[0]             = (_Float16)g[0];
        vd[VT_STRIDE]     = (_Float16)g[1];
        vd[2 * VT_STRIDE] = (_Float16)g[2];
        vd[3 * VT_STRIDE] = (_Float16)g[3];
    }
    __syncthreads();

    _Float16* pw = Pc[wave];
    float*    ow = (float*)pw;                // per-wave 1KB f32 out-stage

    #pragma unroll 1
    for (int si = 0; si < 4; ++si) {
        const int strip = wave * 4 + si;
        const int r0 = strip * 16;            // s2 base for this strip

        // Q as B-operand fragment: B[k=c=quad*8+j][n=s2=n16]
        f16x8 qf;
        qf[0] = (_Float16)qA[0]; qf[1] = (_Float16)qA[1];
        qf[2] = (_Float16)qA[2]; qf[3] = (_Float16)qA[3];
        qf[4] = (_Float16)qB[0]; qf[5] = (_Float16)qB[1];
        qf[6] = (_Float16)qB[2]; qf[7] = (_Float16)qB[3];

        // prefetch next strip's Q (consumed at next iteration's top)
        if (si < 3) {
            const f32x4* qr4 = (const f32x4*)(qb + (size_t)(r0 + 16 + n16) * CC + quad * 8);
            qA = __builtin_nontemporal_load(qr4);
            qB = __builtin_nontemporal_load(qr4 + 1);
        }

        f32x4 o0 = {0.f, 0.f, 0.f, 0.f}, o1 = {0.f, 0.f, 0.f, 0.f};
        float mrow = 0.f;   // valid after hh=0
        float srow = 0.f;

        #pragma unroll
        for (int hh = 0; hh < 2; ++hh) {
            // ---- S^T half: acc[t] row = sk2 = (hh*8+t)*16+quad*4+r, col = s2 = n16 ----
            f32x4 acc[8];
            #pragma unroll
            for (int t = 0; t < 8; ++t) {
                f16x8 kf = *(const f16x8*)&Klds[((hh * 8 + t) * 16 + n16) * CC + quad * 8];
                f32x4 z = {0.f, 0.f, 0.f, 0.f};
                acc[t] = __builtin_amdgcn_mfma_f32_16x16x32_f16(kf, qf, z, 0, 0, 0);
            }

            // ---- bias add: bias[s2 = r0+n16][sk2 = (hh*8+t)*16+quad*4+r] ----
            if (biasT) {
                const f32x4* bb = (const f32x4*)(biasT + ((size_t)h << 16)
                                                 + (size_t)(r0 + n16) * LL) + quad;
                #pragma unroll
                for (int t = 0; t < 8; ++t) {
                    f32x4 bv = bb[(hh * 8 + t) * 4];
                    acc[t][0] += bv[0]; acc[t][1] += bv[1];
                    acc[t][2] += bv[2]; acc[t][3] += bv[3];
                }
            } else {
                const float* bb2 = bias + h + ((size_t)(r0 + n16) * LL + quad * 4) * HH;
                #pragma unroll
                for (int t = 0; t < 8; ++t)
                    #pragma unroll
                    for (int r = 0; r < 4; ++r)
                        acc[t][r] += bb2[((hh * 8 + t) * 16 + r) * HH];
            }

            // ---- local row-max (rows = s2 = n16; quad-uniform after shuffles) ----
            f32x4 mv = acc[0];
            #pragma unroll
            for (int t = 1; t < 8; ++t) {
                mv[0] = fmaxf(mv[0], acc[t][0]); mv[1] = fmaxf(mv[1], acc[t][1]);
                mv[2] = fmaxf(mv[2], acc[t][2]); mv[3] = fmaxf(mv[3], acc[t][3]);
            }
            float ml = fmaxf(fmaxf(mv[0], mv[1]), fmaxf(mv[2], mv[3]));
            ml = fmaxf(ml, __shfl_xor(ml, 16));
            ml = fmaxf(ml, __shfl_xor(ml, 32));

            const float mNew = (hh == 0) ? ml : fmaxf(mrow, ml);

            // ---- exp + local sum ----
            f32x4 sv = {0.f, 0.f, 0.f, 0.f};
            #pragma unroll
            for (int t = 0; t < 8; ++t) {
                #pragma unroll
                for (int r = 0; r < 4; ++r) {
                    float p = exp2f((acc[t][r] - mNew) * 1.44269504f);
                    acc[t][r] = p;
                    sv[r] += p;
                }
            }
            float sl = (sv[0] + sv[1]) + (sv[2] + sv[3]);
            sl += __shfl_xor(sl, 16);
            sl += __shfl_xor(sl, 32);

            if (hh == 0) {
                srow = sl;
            } else {
                const float alpha = exp2f((mrow - mNew) * 1.44269504f);
                srow = srow * alpha + sl;
                // rescale o BEFORE accumulating this half's PV
                #pragma unroll
                for (int r = 0; r < 4; ++r) {
                    const float ar = __shfl(alpha, quad * 4 + r);
                    o0[r] *= ar; o1[r] *= ar;
                }
            }
            mrow = mNew;

            // ---- PV for this half: kk chunks of 32 sk2 ----
            #pragma unroll
            for (int kl = 0; kl < 4; ++kl) {
                const int kg = hh * 4 + kl;
                const int t0 = 2 * kl, t1 = 2 * kl + 1;
                f16x4 pa = { (_Float16)acc[t0][0], (_Float16)acc[t0][1],
                             (_Float16)acc[t0][2], (_Float16)acc[t0][3] };
                f16x4 pb = { (_Float16)acc[t1][0], (_Float16)acc[t1][1],
                             (_Float16)acc[t1][2], (_Float16)acc[t1][3] };
                *(f16x4*)&pw[n16 * PC_STRIDE + quad * 4]      = pa;
                *(f16x4*)&pw[n16 * PC_STRIDE + 16 + quad * 4] = pb;
                // same-wave DS ops are in-order: read sees this chunk's data,
                // and the next chunk's overwrite cannot pass this read.
                f16x8 pf  = *(const f16x8*)&pw[n16 * PC_STRIDE + quad * 8];
                f16x8 vf0 = *(const f16x8*)&Vt[n16 * VT_STRIDE + kg * 32 + quad * 8];
                f16x8 vf1 = *(const f16x8*)&Vt[(16 + n16) * VT_STRIDE + kg * 32 + quad * 8];
                o0 = __builtin_amdgcn_mfma_f32_16x16x32_f16(pf, vf0, o0, 0, 0, 0);
                o1 = __builtin_amdgcn_mfma_f32_16x16x32_f16(pf, vf1, o1, 0, 0, 0);
            }
        }

        // ---- epilogue: normalize + gate in compute layout (registers) ----
        const float inv = 1.f / srow;   // per s2-row (indexed by n16)
        float v0[4], v1[4];
        #pragma unroll
        for (int r = 0; r < 4; ++r) {
            const float wr = __shfl(inv, quad * 4 + r);
            const int s2 = r0 + quad * 4 + r;
            // raw gate, plain loads: lines shared by all 8 h-blocks via L2
            const float g0 = gateb[(s2 * CC + n16) * HH];
            const float g1 = gateb[(s2 * CC + 16 + n16) * HH];
            v0[r] = o0[r] * wr * g0;
            v1[r] = o1[r] * wr * g1;
        }

        // ---- stage 16x32 f32 through per-wave LDS in two 1KB rounds, then
        // store fully-contiguous line-aligned 1KB bursts (kills 64B-segment
        // scatter: WRITE was 4.6x output size + RMW fetches). asm fences pin
        // the f16/f32 LDS type-pun ordering; same-wave DS is HW-in-order. ----
        #pragma unroll
        for (int g = 0; g < 2; ++g) {
            asm volatile("" ::: "memory");
            if ((quad >> 1) == g) {           // quads 2g..2g+1 own rows 8g..8g+7
                const int bq = quad & 1;
                #pragma unroll
                for (int r = 0; r < 4; ++r) {
                    ow[(bq * 4 + r) * 32 + n16]      = v0[r];
                    ow[(bq * 4 + r) * 32 + 16 + n16] = v1[r];
                }
            }
            asm volatile("" ::: "memory");
            f32x4 sv4 = *(const f32x4*)&ow[lane * 4];
            asm volatile("" ::: "memory");
            *((f32x4*)(ob + (size_t)(r0 + g * 8) * CC) + lane) = sv4;
        }
    }
}

extern "C" void kernel_launch(void* const* d_in, const int* in_sizes, int n_in,
                              void* d_out, int out_size, void* d_ws, size_t ws_size,
                              hipStream_t stream) {
    const float* q    = (const float*)d_in[0];
    const float* k    = (const float*)d_in[1];
    const float* v    = (const float*)d_in[2];
    const float* bias = (const float*)d_in[3];
    const float* gate = (const float*)d_in[4];
    float* out = (float*)d_out;

    float* biasT = nullptr;
    if (ws_size >= (size_t)HH * LL * LL * sizeof(float)) {
        biasT = (float*)d_ws;
        bias_transpose<<<dim3((HH * LL * LL) / 256), 256, 0, stream>>>(bias, biasT);
    }
    dim3 grid(LL, HH);
    triattn<<<grid, 256, 0, stream>>>(q, k, v, bias, biasT, gate, out);
}